// Round 12
// baseline (313.118 us; speedup 1.0000x reference)
//
#include <hip/hip_runtime.h>
#include <stdint.h>

// TBN BasicBlock on MI355X, round 12: MX-FP4 datapath (e2m1, unit scales),
// r6's proven conv schedule (single-buffer, 2 barriers/chunk, 2 blocks/CU).
//   out = x + conv3x3(sign(bn2(conv3x3(sign(bn1(x)), tern(w1)))), tern(w2))
// +-1 acts and {-1,0,+1} weights as fp4 e2m1 (+1=0x2, -1=0xA, 0=0x0), alpha
// factored out; mfma_scale_f32_32x32x64_f8f6f4 fmt=4/4 scale=1.0 -> exact
// (f32 accumulation of integer partial sums <= 2304).
// Conv: BM=512 px (16 rows) x BN=64 cout, 8 waves, wave tile 64x64 (2m x 2n
// 32x32 tiles). Per tap: 4 ds_read_b128 (2 A + 2 B) feed 4 MFMAs of K=64.
// K-loop = 4 ci-chunks of 64; all nine tap B-panels LDS-resident per chunk.
// LDS: A [slot2][577px][16B]=18464 + B [tap9][slot2][co64][16B]=18432
//    = 36896 B. Nibble packing: even ci in low nibble everywhere, so A and B
// share the same k ordering (any HW k-permutation cancels in the dot product).

#define EPS 1e-5f

typedef int   i32x4  __attribute__((ext_vector_type(4)));
typedef int   i32x8  __attribute__((ext_vector_type(8)));
typedef float f32x16 __attribute__((ext_vector_type(16)));

__device__ __forceinline__ void gload16(const void* g, void* l) {
  __builtin_amdgcn_global_load_lds(
      (const __attribute__((address_space(1))) void*)g,
      (__attribute__((address_space(3))) void*)l, 16, 0, 0);
}

// fp4 data occupies the low 4 VGPRs of the 8-reg operand; upper half undef.
__device__ __forceinline__ i32x8 ext8(i32x4 v) {
  return __builtin_shufflevector(v, v, 0, 1, 2, 3, -1, -1, -1, -1);
}

// fmt 4 = fp4 e2m1 for both A and B; scale bytes 0x7F (E8M0 127) = 1.0
#define MFMA4(A, B, C) __builtin_amdgcn_mfma_scale_f32_32x32x64_f8f6f4( \
    ext8(A), ext8(B), (C), 4, 4, 0, 127, 0, 127)

// ---------------- stage 1: sum |w| for both weights (grid 72x2) -------------
__global__ __launch_bounds__(256) void wsum_kernel(const float* __restrict__ w1,
                                                   const float* __restrict__ w2,
                                                   float* __restrict__ partial) {
  __shared__ float red[256];
  const int t = threadIdx.x;
  const int b = blockIdx.x;
  const float* w = blockIdx.y ? w2 : w1;
  float s = 0.f;
#pragma unroll
  for (int i = 0; i < 32; ++i) s += fabsf(w[b * 256 + t + i * 18432]);
  red[t] = s;
  __syncthreads();
  for (int o = 128; o > 0; o >>= 1) {
    if (t < o) red[t] += red[t + o];
    __syncthreads();
  }
  if (t == 0) partial[(blockIdx.y << 7) + b] = red[0];
}

__global__ void delta_kernel(const float* __restrict__ p1, const float* __restrict__ p2,
                             float* __restrict__ delta) {
  const int t = threadIdx.x;
  if (t < 2) {
    const float* p = (t == 0) ? p1 : p2;
    double s = 0.0;
    for (int i = 0; i < 72; ++i) s += (double)p[i];
    delta[t] = 0.7f * (float)(s * (1.0 / 589824.0));
  }
}

// ------------- stage 2: quantize both weights to fp4 (grid 1152x2) ----------
// Each thread packs TWO ci (even/odd nibble pair) for one (co, tap).
// Byte layout == conv LDS (staged linearly):
//   nb=co>>6, chunk=ci2>>5, slot=(ci2>>4)&1
//   off = nb*73728 + chunk*18432 + tap*2048 + slot*1024 + (co&63)*16 + (ci2&15)
__global__ __launch_bounds__(256) void quant_kernel(const float* __restrict__ w1,
                                                    const float* __restrict__ w2,
                                                    const float* __restrict__ delta2,
                                                    uint8_t* __restrict__ wq1,
                                                    uint8_t* __restrict__ wq2,
                                                    float* __restrict__ psbase) {
  __shared__ float rs[256];
  __shared__ float rc[256];
  const int t = threadIdx.x;
  const int by = blockIdx.y;
  const float* w = by ? w2 : w1;
  uint8_t* wq = by ? wq2 : wq1;
  const int idx = blockIdx.x * 256 + t;        // 0..294911
  const float d = delta2[by];
  const int co = idx / 1152;
  const int rem = idx - co * 1152;
  const int ci2 = rem / 9;
  const int tap = rem - ci2 * 9;
  const float v0 = w[(co * 256 + 2 * ci2) * 9 + tap];
  const float v1 = w[(co * 256 + 2 * ci2 + 1) * 9 + tap];
  const float a0 = fabsf(v0), a1v = fabsf(v1);
  const bool m0 = a0 > d, m1 = a1v > d;
  const unsigned n0 = m0 ? (v0 > 0.f ? 0x2u : 0xAu) : 0u;
  const unsigned n1 = m1 ? (v1 > 0.f ? 0x2u : 0xAu) : 0u;
  wq[(co >> 6) * 73728 + (ci2 >> 5) * 18432 + tap * 2048 +
     (((ci2 >> 4) & 1) << 10) + ((co & 63) << 4) + (ci2 & 15)] =
      (uint8_t)(n0 | (n1 << 4));
  rs[t] = (m0 ? a0 : 0.f) + (m1 ? a1v : 0.f);
  rc[t] = (m0 ? 1.f : 0.f) + (m1 ? 1.f : 0.f);
  __syncthreads();
  for (int o = 128; o > 0; o >>= 1) {
    if (t < o) { rs[t] += rs[t + o]; rc[t] += rc[t + o]; }
    __syncthreads();
  }
  if (t == 0) { psbase[by * 4608 + blockIdx.x] = rs[0];
                psbase[by * 4608 + 2304 + blockIdx.x] = rc[0]; }
}

__global__ __launch_bounds__(256) void alpha_kernel(const float* __restrict__ ps1, const float* __restrict__ pc1,
                                                    const float* __restrict__ ps2, const float* __restrict__ pc2,
                                                    const float* __restrict__ g2, const float* __restrict__ b2,
                                                    const float* __restrict__ m2, const float* __restrict__ v2,
                                                    float* __restrict__ alphas,
                                                    float* __restrict__ inv2o, float* __restrict__ add2o) {
  __shared__ float rs[256];
  __shared__ float rc[256];
  const int t = threadIdx.x;
  float s1 = 0.f, c1 = 0.f, s2 = 0.f, c2 = 0.f;
#pragma unroll
  for (int i = 0; i < 5; ++i) {
    const int idx = t + (i << 8);
    if (idx < 1152) {
      s1 += ps1[idx]; c1 += pc1[idx];
      s2 += ps2[idx]; c2 += pc2[idx];
    }
  }
  rs[t] = s1; rc[t] = c1;
  __syncthreads();
  for (int o = 128; o > 0; o >>= 1) {
    if (t < o) { rs[t] += rs[t + o]; rc[t] += rc[t + o]; }
    __syncthreads();
  }
  if (t == 0) alphas[0] = rs[0] / fmaxf(rc[0], 1.f);
  __syncthreads();
  rs[t] = s2; rc[t] = c2;
  __syncthreads();
  for (int o = 128; o > 0; o >>= 1) {
    if (t < o) { rs[t] += rs[t + o]; rc[t] += rc[t + o]; }
    __syncthreads();
  }
  if (t == 0) alphas[1] = rs[0] / fmaxf(rc[0], 1.f);
  const float inv = g2[t] * rsqrtf(v2[t] + EPS);
  inv2o[t] = inv;
  add2o[t] = b2[t] - m2[t] * inv;
}

// -------- stage 3: bn1 + binarize + NCHW -> NHWC fp4 nibbles ----------------
__global__ __launch_bounds__(256) void bn_bin_kernel(const float* __restrict__ x,
                                                     const float* __restrict__ g1,
                                                     const float* __restrict__ b1,
                                                     const float* __restrict__ m1,
                                                     const float* __restrict__ v1,
                                                     uint8_t* __restrict__ a1) {
  __shared__ uint8_t lds[64 * 40];   // nibble codes per [pixel][channel]
  const int t = threadIdx.x;
  const int p0 = blockIdx.x << 6;
  const int c0 = blockIdx.y << 5;
  const int n = blockIdx.z;
  const int pl = t & 63;
  const int cl0 = t >> 6;
#pragma unroll
  for (int i = 0; i < 8; ++i) {
    const int cl = cl0 + (i << 2);
    const int c = c0 + cl;
    const float inv = g1[c] * rsqrtf(v1[c] + EPS);
    const float ad = b1[c] - m1[c] * inv;
    const float val = x[(((n << 8) + c) << 10) + p0 + pl];
    const float tt = fmaf(val, inv, ad);
    lds[pl * 40 + cl] = (tt >= 0.f) ? (uint8_t)0x2u : (uint8_t)0xAu;
  }
  __syncthreads();
  // pack 8 channels -> 8 nibbles -> u32; even channel in low nibble
  const int pl2 = t >> 2;
  const int cq = t & 3;
  const uint2 v = *(const uint2*)&lds[pl2 * 40 + (cq << 3)];
  uint32_t out = 0;
#pragma unroll
  for (int j = 0; j < 4; ++j) out |= ((v.x >> (8 * j)) & 0xFu) << (4 * j);
#pragma unroll
  for (int j = 0; j < 4; ++j) out |= ((v.y >> (8 * j)) & 0xFu) << (4 * j + 16);
  *(uint32_t*)&a1[(((n << 10) + p0 + pl2) << 7) + (c0 >> 1) + (cq << 2)] = out;
}

// -------- stages 4/5: per-chunk implicit-GEMM conv3x3 (MX-fp4 MFMA) ---------
template <int EPI>
__global__ __launch_bounds__(512, 4) void conv3x3_tbn(
    const uint8_t* __restrict__ act,   // NHWC fp4 [B*1024][128 B]
    const uint8_t* __restrict__ wq,    // [nb4][chunk4][tap9][slot2][co64][16]
    const float* __restrict__ alphas, const int aidx,
    const float* __restrict__ inv2, const float* __restrict__ add2,  // EPI==0
    const float* __restrict__ xres,                                  // EPI==1
    uint8_t* __restrict__ aout, float* __restrict__ fout) {
  __shared__ uint8_t ldsA[2 * 577 * 16];     // [slot][px 576 + zero][16B]; 18464
  __shared__ uint8_t ldsB[9 * 2 * 64 * 16];  // [tap][slot][co 64][16B];   18432

  const int tid = threadIdx.x;
  const int bid = blockIdx.x;
  const int L = (bid & 7) * 64 + (bid >> 3);  // XCD swizzle, 512 blocks
  const int mb = L >> 2;            // 128 pixel tiles (16 image rows each)
  const int nb = L & 3;             // cout quarter (64 couts)
  const int n = mb >> 1;
  const int y0 = (mb & 1) << 4;
  const int l = tid & 63;
  const int wid = tid >> 6;         // 8 waves, 2 image rows each
  const int lx = l & 31;            // x position / co lane
  const int lh = l >> 5;            // k-half selector

  // ---- A staging: 1152 granules = [slot 2][px 576], 16B each ----
  int srcA[3], dstA[3];
#pragma unroll
  for (int i = 0; i < 3; ++i) {
    const int idx = tid + (i << 9);
    const int sl = idx / 576;
    const int px = idx - sl * 576;
    int ys = y0 - 1 + (px >> 5);
    ys = ys < 0 ? 0 : (ys > 31 ? 31 : ys);  // clamp (OOB rows only read via zero-px)
    srcA[i] = (((n << 10) + (ys << 5) + (px & 31)) << 7) + (sl << 4);
    dstA[i] = sl * 9232 + (px << 4);
  }
  if (tid < 2) *(i32x4*)(ldsA + tid * 9232 + 9216) = (i32x4){0, 0, 0, 0};

  f32x16 acc[2][2];
  acc[0][0] = (f32x16)(0.f); acc[0][1] = (f32x16)(0.f);
  acc[1][0] = (f32x16)(0.f); acc[1][1] = (f32x16)(0.f);

  const uint8_t* wnb = wq + nb * 73728;

#define STAGE(CH) do {                                                      \
  const uint8_t* wch = wnb + (CH) * 18432;                                  \
  _Pragma("unroll")                                                         \
  for (int i = 0; i < 3; ++i) {                                             \
    if (i < 2 || tid < 128) {                                               \
      gload16(act + srcA[i] + ((CH) << 5), ldsA + dstA[i]);                 \
      const int j = tid + (i << 9);                                         \
      gload16(wch + (j << 4), ldsB + (j << 4));                             \
    }                                                                       \
  }                                                                         \
} while (0)

  STAGE(0);
  __syncthreads();  // implicit vmcnt(0): staged data visible

  for (int chunk = 0; chunk < 4; ++chunk) {
    __builtin_amdgcn_s_setprio(1);
    // ---- barrier-free 9-tap compute over resident chunk ----
#pragma unroll
    for (int tap = 0; tap < 9; ++tap) {
      const int ky = tap / 3, kx = tap % 3;
      const int xs = lx + kx - 1;
      const bool xok = (unsigned)xs < 32u;
      int apix[2];
#pragma unroll
      for (int mt = 0; mt < 2; ++mt) {
        const int yr = (wid << 1) + mt + ky;       // A-tile row 0..17
        const bool ok = xok && ((unsigned)(y0 - 1 + yr) < 32u);
        apix[mt] = ok ? (yr << 5) + xs : 576;      // zero-px for halo
      }
      i32x4 af[2], bf[2];
#pragma unroll
      for (int mt = 0; mt < 2; ++mt)
        af[mt] = *(const i32x4*)(ldsA + lh * 9232 + (apix[mt] << 4));
#pragma unroll
      for (int nt = 0; nt < 2; ++nt)
        bf[nt] = *(const i32x4*)(ldsB + (tap << 11) + (lh << 10) + (((nt << 5) + lx) << 4));
#pragma unroll
      for (int mt = 0; mt < 2; ++mt)
#pragma unroll
        for (int nt = 0; nt < 2; ++nt)
          acc[mt][nt] = MFMA4(af[mt], bf[nt], acc[mt][nt]);
    }
    __builtin_amdgcn_s_setprio(0);
    // ---- restage for next chunk ----
    if (chunk < 3) {
      __syncthreads();  // all waves done reading this chunk
      STAGE(chunk + 1);
      __syncthreads();  // drain
    }
  }

  // C/D (32x32): n(co) = lane&31, m(px) = (reg&3) + 8*(reg>>2) + 4*(lane>>5)
  const float alpha = alphas[aidx];
  if constexpr (EPI == 0) {
#define EPI0(ACC, MT, NT) {                                                  \
    const int co = (nb << 6) + ((NT) << 5) + lx;                             \
    const float inv = inv2[co];                                              \
    const float ad = add2[co];                                               \
    const int pixbase = (mb << 9) + (((wid << 1) + (MT)) << 5) + (lh << 2);  \
    _Pragma("unroll")                                                        \
    for (int rg = 0; rg < 16; ++rg) {                                        \
      const int pix = pixbase + (rg & 3) + ((rg >> 2) << 3);                 \
      const float tt = fmaf(alpha * ACC[rg], inv, ad);                       \
      const unsigned nib = (tt >= 0.f) ? 0x2u : 0xAu;                        \
      const unsigned oth = (unsigned)__shfl_xor((int)nib, 1);                \
      if ((lx & 1) == 0)                                                     \
        aout[(pix << 7) + (co >> 1)] = (uint8_t)(nib | (oth << 4));          \
    } }
    EPI0(acc[0][0], 0, 0); EPI0(acc[0][1], 0, 1);
    EPI0(acc[1][0], 1, 0); EPI0(acc[1][1], 1, 1);
  } else {
#define EPI1(ACC, MT, NT) {                                                  \
    const int co = (nb << 6) + ((NT) << 5) + lx;                             \
    const int pimg0 = ((mb & 1) << 9) + (((wid << 1) + (MT)) << 5) + (lh << 2); \
    _Pragma("unroll")                                                        \
    for (int qd = 0; qd < 4; ++qd) {                                         \
      const int off = (((n << 8) + co) << 10) + pimg0 + (qd << 3);           \
      const float4 xv = *(const float4*)(xres + off);                        \
      float4 o;                                                              \
      o.x = xv.x + alpha * ACC[qd * 4 + 0];                                  \
      o.y = xv.y + alpha * ACC[qd * 4 + 1];                                  \
      o.z = xv.z + alpha * ACC[qd * 4 + 2];                                  \
      o.w = xv.w + alpha * ACC[qd * 4 + 3];                                  \
      *(float4*)(fout + off) = o;                                            \
    } }
    EPI1(acc[0][0], 0, 0); EPI1(acc[0][1], 0, 1);
    EPI1(acc[1][0], 1, 0); EPI1(acc[1][1], 1, 1);
  }
#undef STAGE
}

extern "C" void kernel_launch(void* const* d_in, const int* in_sizes, int n_in,
                              void* d_out, int out_size, void* d_ws, size_t ws_size,
                              hipStream_t stream) {
  const float* x  = (const float*)d_in[0];
  const float* g1 = (const float*)d_in[1];
  const float* b1 = (const float*)d_in[2];
  const float* m1 = (const float*)d_in[3];
  const float* v1 = (const float*)d_in[4];
  const float* w1 = (const float*)d_in[5];
  const float* g2 = (const float*)d_in[6];
  const float* b2 = (const float*)d_in[7];
  const float* m2 = (const float*)d_in[8];
  const float* v2 = (const float*)d_in[9];
  const float* w2 = (const float*)d_in[10];
  float* out = (float*)d_out;

  char* ws = (char*)d_ws;
  uint8_t* a1  = (uint8_t*)(ws);                      // 8 MB (fp4 NHWC)
  uint8_t* a2  = (uint8_t*)(ws + 8388608);            // 8 MB
  uint8_t* wq1 = (uint8_t*)(ws + 16777216);           // 294912 B
  uint8_t* wq2 = (uint8_t*)(ws + 16777216 + 294912);  // 294912 B
  float* fs = (float*)(ws + 16777216 + 589824);
  float* pd1    = fs;          // 72 entries
  float* pd2    = fs + 128;    // 72 entries
  float* deltas = fs + 256;
  float* alphas = fs + 260;
  float* psb    = fs + 512;    // ps1[1152]@0, pc1@2304, ps2@4608, pc2@6912
  float* inv2   = fs + 512 + 9216;
  float* add2   = fs + 512 + 9472;

  hipLaunchKernelGGL(wsum_kernel, dim3(72, 2), dim3(256), 0, stream, w1, w2, fs);
  hipLaunchKernelGGL(delta_kernel, dim3(1), dim3(64), 0, stream, pd1, pd2, deltas);
  hipLaunchKernelGGL(quant_kernel, dim3(1152, 2), dim3(256), 0, stream,
                     w1, w2, deltas, wq1, wq2, psb);
  hipLaunchKernelGGL(alpha_kernel, dim3(1), dim3(256), 0, stream,
                     psb, psb + 2304, psb + 4608, psb + 6912,
                     g2, b2, m2, v2, alphas, inv2, add2);
  hipLaunchKernelGGL(bn_bin_kernel, dim3(16, 8, 64), dim3(256), 0, stream, x, g1, b1, m1, v1, a1);
  hipLaunchKernelGGL((conv3x3_tbn<0>), dim3(512), dim3(512), 0, stream,
                     a1, wq1, alphas, 0, inv2, add2, (const float*)nullptr,
                     a2, (float*)nullptr);
  hipLaunchKernelGGL((conv3x3_tbn<1>), dim3(512), dim3(512), 0, stream,
                     a2, wq2, alphas, 1, (const float*)nullptr, (const float*)nullptr, x,
                     (uint8_t*)nullptr, out);
  (void)in_sizes; (void)n_in; (void)out_size; (void)ws_size;
}